// Round 11
// baseline (103.490 us; speedup 1.0000x reference)
//
#include <hip/hip_runtime.h>
#include <hip/hip_bf16.h>
#include <math.h>

// x: [128, 8192] f32, scale_weights: [32] f32, out: [128, 32] f32
// coef[t,s] = sum_{j=0}^{255} bank[j][s] * Xpad[t+j],  Xpad[i] = x[i-128] (zero outside)
// out[b][s] = (sum_t coef^2 / NT) * softmax(sw)[s]
#define NT      8192
#define NS      32
#define KTAPS   256
#define TQ      2048            // t-range per block (4 blocks per row)
#define XELEM   (TQ + KTAPS)    // 2304 Xpad elems per block
#define XSTRIDE 2320            // +16 pad: copy stride = 1160 words == 8 mod 32 (uniform banks)
#define NCOPY   4
#define BLOCK   512

typedef __attribute__((ext_vector_type(8)))  short bf16x8;
typedef __attribute__((ext_vector_type(4)))  short short4v;
typedef __attribute__((ext_vector_type(16))) float f32x16;
typedef __attribute__((ext_vector_type(4)))  float float4v;

// Single node. Compute core = R9's proven kernel (25.3 us config, grid 512).
// Cross-block combine via ticket with PROPER device-scope fencing:
//   storers' visibility: plain store -> __threadfence() (by storing threads)
//   -> __syncthreads() -> tid0 atomicAdd (device scope) -> last block
//   (__threadfence() + ACQUIRE loads, fixed summation order) -> out[b][:].
// Ticket residue (old&3)==3 fires exactly once per row per call for ANY
// initial cnt value (+4/call preserves residue across unpoisoned replays).
__global__ __launch_bounds__(BLOCK, 2)
void cwt_fused_kernel(const float* __restrict__ x,
                      const float* __restrict__ sw,
                      float* __restrict__ part,        // [128][4][32] in d_ws
                      unsigned int* __restrict__ cnt,  // [128] in d_ws
                      float* __restrict__ out)
{
    __shared__ unsigned short AW[8192];             // 16 KB bank fragments
    __shared__ unsigned short XL[NCOPY * XSTRIDE];  // 18.1 KB x shift-copies
    __shared__ float redE[8 * 2 * 16];
    __shared__ int lastFlag;

    const int tid = threadIdx.x;
    const int b   = blockIdx.x >> 2;
    const int qt  = blockIdx.x & 3;
    const int T0  = qt * TQ;

    // ---- phase 0a: bank fragments in exact MFMA A-layout (HW intrinsics) ----
    // lane l holds A[m=l&31][k=16*kap+8*(l>>5)+j] at AW[kap*512 + l*8 + j]
    {
        unsigned short vb[16];
        #pragma unroll
        for (int i = 0; i < 16; ++i) {
            int e   = tid * 16 + i;
            int kap = e >> 9;
            int l   = (e >> 3) & 63;
            int j   = e & 7;
            int sc  = (l & 31) + 1;
            int k   = kap * 16 + ((l >> 5) << 3) + j;
            int L   = 8 * sc;
            int u   = k - (128 - 4 * sc);
            float val = 0.f;
            if (u >= 0 && u < L) {
                float tau = fmaf(8.0f / (float)(L - 1), (float)u, -4.0f);
                val = __expf(-0.5f * tau * tau) * __cosf(5.0f * tau)
                      * __frsqrt_rn((float)sc);
            }
            __hip_bfloat16 bv = __float2bfloat16(val);
            vb[i] = *reinterpret_cast<unsigned short*>(&bv);
        }
        #pragma unroll
        for (int h = 0; h < 4; ++h)
            *reinterpret_cast<short4v*>(&AW[tid * 16 + 4 * h]) =
                *reinterpret_cast<short4v*>(&vb[4 * h]);
    }

    // ---- phase 0b: stage XL[c][i] = bf16(Xpad[T0 + i + c]), i in [0, XELEM) ----
    const float* xrow = x + (size_t)b * NT;
    for (int q = tid; q < XELEM / 4; q += BLOCK) {
        float v[8];
        #pragma unroll
        for (int h = 0; h < 2; ++h) {
            int xi = T0 + 4 * (q + h) - 128;        // multiple of 4
            float4v f;
            if (xi >= 0 && xi <= NT - 4) f = *reinterpret_cast<const float4v*>(xrow + xi);
            else { f[0] = 0.f; f[1] = 0.f; f[2] = 0.f; f[3] = 0.f; }
            v[4 * h + 0] = f[0]; v[4 * h + 1] = f[1];
            v[4 * h + 2] = f[2]; v[4 * h + 3] = f[3];
        }
        unsigned short ub[8];
        #pragma unroll
        for (int i = 0; i < 8; ++i) {
            __hip_bfloat16 t = __float2bfloat16(v[i]);
            ub[i] = *reinterpret_cast<unsigned short*>(&t);
        }
        #pragma unroll
        for (int c = 0; c < NCOPY; ++c) {
            short4v w;
            w[0] = (short)ub[c + 0]; w[1] = (short)ub[c + 1];
            w[2] = (short)ub[c + 2]; w[3] = (short)ub[c + 3];
            *reinterpret_cast<short4v*>(&XL[c * XSTRIDE + 4 * q]) = w;
        }
    }
    __syncthreads();

    // ---- phase 1: MFMA k-loop ----
    const int wv   = tid >> 6;                      // wave 0..7: t-macro [256*wv, +256)
    const int lane = tid & 63;
    const int n    = lane & 31;                     // B column (t within tile)
    const int hh   = lane >> 5;                     // k-half

    const unsigned short* xc = &XL[(n & 3) * XSTRIDE];
    const int ibase = 256 * wv + 4 * (n >> 2) + 8 * hh;

    f32x16 zz;
    #pragma unroll
    for (int r = 0; r < 16; ++r) zz[r] = 0.f;
    f32x16 acc[8];
    #pragma unroll
    for (int m = 0; m < 8; ++m) acc[m] = zz;

    bf16x8 ring[16];
    #define LOADB(D) ({                                                              \
        short4v lo_ = *reinterpret_cast<const short4v*>(xc + ibase + 16 * (D));      \
        short4v hi_ = *reinterpret_cast<const short4v*>(xc + ibase + 16 * (D) + 4);  \
        __builtin_shufflevector(lo_, hi_, 0, 1, 2, 3, 4, 5, 6, 7); })

    #pragma unroll
    for (int D = 0; D < 14; ++D) ring[D] = LOADB(D);

    const unsigned short* ap = AW + lane * 8;
    #pragma unroll
    for (int kap = 0; kap < 16; ++kap) {
        bf16x8 afrag = *reinterpret_cast<const bf16x8*>(ap + kap * 512);
        ring[(kap + 14) & 15] = LOADB(kap + 14);
        #pragma unroll
        for (int m = 0; m < 8; ++m)
            acc[m] = __builtin_amdgcn_mfma_f32_32x32x16_bf16(
                         afrag, ring[(kap + 2 * m) & 15], acc[m], 0, 0, 0);
    }

    // ---- phase 2: energy partials; C layout: col(t)=lane&31, s=(r&3)+8*(r>>2)+4*hh ----
    float ep[16];
    #pragma unroll
    for (int r = 0; r < 16; ++r) {
        float s2 = 0.f;
        #pragma unroll
        for (int m = 0; m < 8; ++m) s2 = fmaf(acc[m][r], acc[m][r], s2);
        ep[r] = s2;
    }
    #pragma unroll
    for (int r = 0; r < 16; ++r) {
        ep[r] += __shfl_xor(ep[r], 16);
        ep[r] += __shfl_xor(ep[r], 8);
        ep[r] += __shfl_xor(ep[r], 4);
        ep[r] += __shfl_xor(ep[r], 2);
        ep[r] += __shfl_xor(ep[r], 1);
    }
    if ((lane & 31) == 0) {
        #pragma unroll
        for (int r = 0; r < 16; ++r) redE[(wv * 2 + hh) * 16 + r] = ep[r];
    }
    __syncthreads();

    // ---- phase 3: partial -> ws (plain store), fence, ticket, combine ----
    if (tid < 32) {
        int s  = tid;
        int r  = (s >> 3) * 4 + (s & 3);
        int hi = (s >> 2) & 1;
        float tot = 0.f;
        #pragma unroll
        for (int w = 0; w < 8; ++w) tot += redE[(w * 2 + hi) * 16 + r];
        part[(b * 4 + qt) * 32 + s] = tot;
    }
    __threadfence();           // device-scope release, executed by the storers
    __syncthreads();           // all storers' fences complete before ticket
    if (tid == 0) {
        unsigned int old = atomicAdd(&cnt[b], 1u);   // device-scope (m20)
        lastFlag = ((old & 3u) == 3u) ? 1 : 0;       // unique for ANY initial value
    }
    __syncthreads();
    if (lastFlag) {
        __threadfence();       // acquire side: see other blocks' released stores
        if (tid < 32) {
            int s = tid;
            float tot = 0.f;
            #pragma unroll
            for (int q = 0; q < 4; ++q)              // fixed order: deterministic
                tot += __hip_atomic_load(&part[(b * 4 + q) * 32 + s],
                                         __ATOMIC_ACQUIRE, __HIP_MEMORY_SCOPE_AGENT);
            float mx = -1e30f;
            for (int i = 0; i < NS; ++i) mx = fmaxf(mx, sw[i]);
            float den = 0.f;
            for (int i = 0; i < NS; ++i) den += __expf(sw[i] - mx);
            float soft = __expf(sw[s] - mx) / den;
            out[b * NS + s] = tot * (1.0f / (float)NT) * soft;
        }
    }
}

extern "C" void kernel_launch(void* const* d_in, const int* in_sizes, int n_in,
                              void* d_out, int out_size, void* d_ws, size_t ws_size,
                              hipStream_t stream) {
    const float* x  = (const float*)d_in[0];
    const float* sw = (const float*)d_in[1];
    float* out = (float*)d_out;
    float*        part = (float*)d_ws;                         // 64 KB
    unsigned int* cnt  = (unsigned int*)((char*)d_ws + 65536); // 512 B
    hipLaunchKernelGGL(cwt_fused_kernel, dim3(512), dim3(BLOCK), 0, stream,
                       x, sw, part, cnt, out);
}

// Round 12
// 25.235 us; speedup vs baseline: 4.1010x; 4.1010x over previous
//
#include <hip/hip_runtime.h>
#include <hip/hip_bf16.h>
#include <math.h>

// x: [128, 8192] f32, scale_weights: [32] f32, out: [128, 32] f32
// coef[t,s] = sum_{j=0}^{255} bank[j][s] * Xpad[t+j],  Xpad[i] = x[i-128] (zero outside)
// out[b][s] = (sum_t coef^2 / NT) * softmax(sw)[s]
#define NT      8192
#define NS      32
#define KTAPS   256
#define TQ      2048            // t-range per block (4 blocks per row)
#define XELEM   (TQ + KTAPS)    // 2304 Xpad elems per block
#define XSTRIDE 2320            // +16 pad: copy stride = 1160 words == 8 mod 32 (uniform banks)
#define NCOPY   4
#define BLOCK   512

typedef __attribute__((ext_vector_type(8)))  short bf16x8;
typedef __attribute__((ext_vector_type(4)))  short short4v;
typedef __attribute__((ext_vector_type(16))) float f32x16;
typedef __attribute__((ext_vector_type(4)))  float float4v;

// Node 1: main kernel — proven R9 configuration (25.3 us session best).
// Bank generation with HW transcendentals, fused; combine stays a separate
// graph node (cross-XCD dataflow via plain stores + node boundary — the
// only correct-AND-cheap option per R6/R11 evidence).
__global__ __launch_bounds__(BLOCK, 2)
void cwt_mfma_kernel(const float* __restrict__ x,
                     float* __restrict__ part)       // [128][4][32] in d_ws
{
    __shared__ unsigned short AW[8192];             // 16 KB bank fragments
    __shared__ unsigned short XL[NCOPY * XSTRIDE];  // 18.1 KB x shift-copies
    __shared__ float redE[8 * 2 * 16];

    const int tid = threadIdx.x;
    const int b   = blockIdx.x >> 2;
    const int qt  = blockIdx.x & 3;
    const int T0  = qt * TQ;

    // ---- phase 0a: bank fragments in exact MFMA A-layout (HW intrinsics) ----
    // lane l holds A[m=l&31][k=16*kap+8*(l>>5)+j] at AW[kap*512 + l*8 + j]
    {
        unsigned short vb[16];
        #pragma unroll
        for (int i = 0; i < 16; ++i) {
            int e   = tid * 16 + i;
            int kap = e >> 9;
            int l   = (e >> 3) & 63;
            int j   = e & 7;
            int sc  = (l & 31) + 1;
            int k   = kap * 16 + ((l >> 5) << 3) + j;
            int L   = 8 * sc;
            int u   = k - (128 - 4 * sc);
            float val = 0.f;
            if (u >= 0 && u < L) {
                float tau = fmaf(8.0f / (float)(L - 1), (float)u, -4.0f);
                val = __expf(-0.5f * tau * tau) * __cosf(5.0f * tau)
                      * __frsqrt_rn((float)sc);
            }
            __hip_bfloat16 bv = __float2bfloat16(val);
            vb[i] = *reinterpret_cast<unsigned short*>(&bv);
        }
        #pragma unroll
        for (int h = 0; h < 4; ++h)
            *reinterpret_cast<short4v*>(&AW[tid * 16 + 4 * h]) =
                *reinterpret_cast<short4v*>(&vb[4 * h]);
    }

    // ---- phase 0b: stage XL[c][i] = bf16(Xpad[T0 + i + c]), i in [0, XELEM) ----
    const float* xrow = x + (size_t)b * NT;
    for (int q = tid; q < XELEM / 4; q += BLOCK) {
        float v[8];
        #pragma unroll
        for (int h = 0; h < 2; ++h) {
            int xi = T0 + 4 * (q + h) - 128;        // multiple of 4
            float4v f;
            if (xi >= 0 && xi <= NT - 4) f = *reinterpret_cast<const float4v*>(xrow + xi);
            else { f[0] = 0.f; f[1] = 0.f; f[2] = 0.f; f[3] = 0.f; }
            v[4 * h + 0] = f[0]; v[4 * h + 1] = f[1];
            v[4 * h + 2] = f[2]; v[4 * h + 3] = f[3];
        }
        unsigned short ub[8];
        #pragma unroll
        for (int i = 0; i < 8; ++i) {
            __hip_bfloat16 t = __float2bfloat16(v[i]);
            ub[i] = *reinterpret_cast<unsigned short*>(&t);
        }
        #pragma unroll
        for (int c = 0; c < NCOPY; ++c) {
            short4v w;
            w[0] = (short)ub[c + 0]; w[1] = (short)ub[c + 1];
            w[2] = (short)ub[c + 2]; w[3] = (short)ub[c + 3];
            *reinterpret_cast<short4v*>(&XL[c * XSTRIDE + 4 * q]) = w;
        }
    }
    __syncthreads();

    // ---- phase 1: MFMA k-loop ----
    const int wv   = tid >> 6;                      // wave 0..7: t-macro [256*wv, +256)
    const int lane = tid & 63;
    const int n    = lane & 31;                     // B column (t within tile)
    const int hh   = lane >> 5;                     // k-half

    const unsigned short* xc = &XL[(n & 3) * XSTRIDE];
    const int ibase = 256 * wv + 4 * (n >> 2) + 8 * hh;

    f32x16 zz;
    #pragma unroll
    for (int r = 0; r < 16; ++r) zz[r] = 0.f;
    f32x16 acc[8];
    #pragma unroll
    for (int m = 0; m < 8; ++m) acc[m] = zz;

    bf16x8 ring[16];
    #define LOADB(D) ({                                                              \
        short4v lo_ = *reinterpret_cast<const short4v*>(xc + ibase + 16 * (D));      \
        short4v hi_ = *reinterpret_cast<const short4v*>(xc + ibase + 16 * (D) + 4);  \
        __builtin_shufflevector(lo_, hi_, 0, 1, 2, 3, 4, 5, 6, 7); })

    #pragma unroll
    for (int D = 0; D < 14; ++D) ring[D] = LOADB(D);

    const unsigned short* ap = AW + lane * 8;
    #pragma unroll
    for (int kap = 0; kap < 16; ++kap) {
        bf16x8 afrag = *reinterpret_cast<const bf16x8*>(ap + kap * 512);
        ring[(kap + 14) & 15] = LOADB(kap + 14);
        #pragma unroll
        for (int m = 0; m < 8; ++m)
            acc[m] = __builtin_amdgcn_mfma_f32_32x32x16_bf16(
                         afrag, ring[(kap + 2 * m) & 15], acc[m], 0, 0, 0);
    }

    // ---- phase 2: energy partials; C layout: col(t)=lane&31, s=(r&3)+8*(r>>2)+4*hh ----
    float ep[16];
    #pragma unroll
    for (int r = 0; r < 16; ++r) {
        float s2 = 0.f;
        #pragma unroll
        for (int m = 0; m < 8; ++m) s2 = fmaf(acc[m][r], acc[m][r], s2);
        ep[r] = s2;
    }
    #pragma unroll
    for (int r = 0; r < 16; ++r) {
        ep[r] += __shfl_xor(ep[r], 16);
        ep[r] += __shfl_xor(ep[r], 8);
        ep[r] += __shfl_xor(ep[r], 4);
        ep[r] += __shfl_xor(ep[r], 2);
        ep[r] += __shfl_xor(ep[r], 1);
    }
    if ((lane & 31) == 0) {
        #pragma unroll
        for (int r = 0; r < 16; ++r) redE[(wv * 2 + hh) * 16 + r] = ep[r];
    }
    __syncthreads();
    if (tid < 32) {
        int s  = tid;
        int r  = (s >> 3) * 4 + (s & 3);
        int hi = (s >> 2) & 1;
        float tot = 0.f;
        #pragma unroll
        for (int w = 0; w < 8; ++w) tot += redE[(w * 2 + hi) * 16 + r];
        part[(b * 4 + qt) * 32 + s] = tot;          // plain store (proven)
    }
}

// Node 2: combine partials, apply softmax (proven; HW exp).
__global__ void combine_kernel(const float* __restrict__ part,
                               const float* __restrict__ sw,
                               float* __restrict__ out) {
    int g = blockIdx.x * 256 + threadIdx.x;
    if (g >= 128 * 32) return;
    int b = g >> 5, s = g & 31;
    float mx = -1e30f;
    for (int i = 0; i < NS; ++i) mx = fmaxf(mx, sw[i]);
    float den = 0.f;
    for (int i = 0; i < NS; ++i) den += __expf(sw[i] - mx);
    float soft = __expf(sw[s] - mx) / den;
    float tot = 0.f;
    #pragma unroll
    for (int qv = 0; qv < 4; ++qv) tot += part[(b * 4 + qv) * 32 + s];
    out[g] = tot * (1.0f / (float)NT) * soft;
}

extern "C" void kernel_launch(void* const* d_in, const int* in_sizes, int n_in,
                              void* d_out, int out_size, void* d_ws, size_t ws_size,
                              hipStream_t stream) {
    const float* x  = (const float*)d_in[0];
    const float* sw = (const float*)d_in[1];
    float* out  = (float*)d_out;
    float* part = (float*)d_ws;                      // 64 KB scratch
    hipLaunchKernelGGL(cwt_mfma_kernel, dim3(512), dim3(BLOCK), 0, stream, x, part);
    hipLaunchKernelGGL(combine_kernel, dim3(16), dim3(256), 0, stream, part, sw, out);
}